// Round 6
// baseline (760.340 us; speedup 1.0000x reference)
//
#include <hip/hip_runtime.h>
#include <cmath>

#define NB 32
#define NL 512
#define ND 768
#define NK 8192
#define NM (NB*NL)        // 16384 max rows
#define BM 128
#define BN 128
#define NDSTEP (ND/32)    // 24 d-steps of BK=32
#define KSPLIT 16
#define KSLICE (NK/KSPLIT)   // fallback path: 512-wide k-slices

typedef __attribute__((ext_vector_type(8))) short bf16x8;
typedef __attribute__((ext_vector_type(4))) float f32x4;
typedef unsigned short u16;

// async global->LDS, 16B per lane. dest must be wave-uniform; HW adds lane*16.
__device__ __forceinline__ void gload16(const void* g, void* s) {
  __builtin_amdgcn_global_load_lds(
      (const __attribute__((address_space(1))) char*)g,
      (__attribute__((address_space(3))) char*)s, 16, 0, 0);
}

// split fp32 pair into hi/lo bf16 pairs (packed)
__device__ __forceinline__ void split_pk(float x0, float x1, unsigned &h, unsigned &l) {
  unsigned hp;
  asm("v_cvt_pk_bf16_f32 %0, %1, %2" : "=v"(hp) : "v"(x0), "v"(x1));
  union { unsigned u; float f; } f0, f1;
  f0.u = hp << 16;
  f1.u = hp & 0xffff0000u;
  unsigned lp;
  float r0 = x0 - f0.f, r1 = x1 - f1.f;
  asm("v_cvt_pk_bf16_f32 %0, %1, %2" : "=v"(lp) : "v"(r0), "v"(r1));
  h = hp; l = lp;
}

// One BK=32 step: 16 ds_read_b128 + 48 MFMAs (3-product split-bf16).
// psl = fq ^ ((fr>>1)&3) : physical slot for this lane's logical k-slot fq.
__device__ __forceinline__ void mfma_step(const u16* Ah, const u16* Al,
                                          const u16* Bh, const u16* Bl,
                                          int wm, int wn, int fr, int psl,
                                          f32x4 acc[4][4]) {
  bf16x8 aH[4], aL[4], bH[4], bL[4];
#pragma unroll
  for (int i = 0; i < 4; ++i) {
    int ar = (wm*64 + i*16 + fr)*32 + psl*8;
    int br = (wn*64 + i*16 + fr)*32 + psl*8;
    aH[i] = *(const bf16x8*)&Ah[ar];
    aL[i] = *(const bf16x8*)&Al[ar];
    bH[i] = *(const bf16x8*)&Bh[br];
    bL[i] = *(const bf16x8*)&Bl[br];
  }
  __builtin_amdgcn_s_setprio(1);
#pragma unroll
  for (int mi = 0; mi < 4; ++mi)
#pragma unroll
    for (int ni = 0; ni < 4; ++ni) {
      acc[mi][ni] = __builtin_amdgcn_mfma_f32_16x16x32_bf16(aH[mi], bH[ni], acc[mi][ni], 0, 0, 0);
      acc[mi][ni] = __builtin_amdgcn_mfma_f32_16x16x32_bf16(aH[mi], bL[ni], acc[mi][ni], 0, 0, 0);
      acc[mi][ni] = __builtin_amdgcn_mfma_f32_16x16x32_bf16(aL[mi], bH[ni], acc[mi][ni], 0, 0, 0);
    }
  __builtin_amdgcn_s_setprio(0);
}

// ---------------------------------------------------------------------------
// Kernel 0: global compaction of valid rows (batch-major).
// ---------------------------------------------------------------------------
__global__ __launch_bounds__(512)
void compact_all(const int* __restrict__ mask, int* __restrict__ vg,
                 int* __restrict__ cntb, int* __restrict__ offb,
                 int* __restrict__ total) {
  __shared__ int wcnt[8], woff[8];
  __shared__ int base;
  int t = threadIdx.x;
  if (t == 0) base = 0;
  __syncthreads();
  for (int b = 0; b < NB; ++b) {
    int v = (mask[b*NL + t] != 0) ? 1 : 0;
    unsigned long long bal = __ballot(v);
    int lane = t & 63, wv = t >> 6;
    int pos = __popcll(bal & ((1ull << lane) - 1ull));
    if (lane == 0) wcnt[wv] = __popcll(bal);
    __syncthreads();
    if (t == 0) {
      int s = 0;
#pragma unroll
      for (int w = 0; w < 8; ++w) { woff[w] = s; s += wcnt[w]; }
      cntb[b] = s; offb[b] = base;
    }
    __syncthreads();
    if (v) vg[base + woff[wv] + pos] = b*NL + t;
    __syncthreads();
    if (t == 0) base += cntb[b];
    __syncthreads();
  }
  if (t == 0) total[0] = base;
}

// ---------------------------------------------------------------------------
// Convert Q -> compacted-row-major bf16 hi/lo.
// ---------------------------------------------------------------------------
__global__ __launch_bounds__(256)
void convert_q(const float* __restrict__ q, const int* __restrict__ vg,
               const int* __restrict__ total_p,
               u16* __restrict__ Qh, u16* __restrict__ Ql) {
  int total = total_p[0];
  int cid = blockIdx.x * 256 + threadIdx.x;       // chunk of 8 elements
  int row = cid / (ND/8), c = cid % (ND/8);
  if (row >= total) return;
  const float* src = q + (size_t)vg[row] * ND + c*8;
  float4 v0 = ((const float4*)src)[0], v1 = ((const float4*)src)[1];
  unsigned h[4], l[4];
  split_pk(v0.x, v0.y, h[0], l[0]); split_pk(v0.z, v0.w, h[1], l[1]);
  split_pk(v1.x, v1.y, h[2], l[2]); split_pk(v1.z, v1.w, h[3], l[3]);
  size_t o = (size_t)row * ND + c*8;
  *(uint4*)(Qh + o) = make_uint4(h[0], h[1], h[2], h[3]);
  *(uint4*)(Ql + o) = make_uint4(l[0], l[1], l[2], l[3]);
}

// ---------------------------------------------------------------------------
// Convert P -> tiled + pre-swizzled bf16 hi/lo.
// ---------------------------------------------------------------------------
__global__ __launch_bounds__(256)
void convert_p(const float* __restrict__ p,
               u16* __restrict__ Pht, u16* __restrict__ Plt) {
  int cid = blockIdx.x * 256 + threadIdx.x;        // 64*24*512 chunks
  int kt = cid / (NDSTEP*512);
  int rem = cid % (NDSTEP*512);
  int dt = rem / 512, c = rem % 512;
  int r = c >> 2, sp = c & 3;
  int sl = sp ^ ((r >> 1) & 3);
  const float* src = p + (size_t)(kt*128 + r) * ND + dt*32 + sl*8;
  float4 v0 = ((const float4*)src)[0], v1 = ((const float4*)src)[1];
  unsigned h[4], l[4];
  split_pk(v0.x, v0.y, h[0], l[0]); split_pk(v0.z, v0.w, h[1], l[1]);
  split_pk(v1.x, v1.y, h[2], l[2]); split_pk(v1.z, v1.w, h[3], l[3]);
  size_t o = (size_t)cid * 8;
  *(uint4*)(Pht + o) = make_uint4(h[0], h[1], h[2], h[3]);
  *(uint4*)(Plt + o) = make_uint4(l[0], l[1], l[2], l[3]);
}

// ===========================================================================
// STREAMING PATH: pass1s stores fp32 logits + per-(rowtile,ktile) m/Z
// partials; combines -> c = m + log Z; pass2s streams logits for col-max.
// ===========================================================================

// Grid 8192: kt = xcd-shuffled low 6 bits, rt = bid>>6 in [0,128).
__global__ __launch_bounds__(256, 2)
void pass1s(const u16* __restrict__ Qh, const u16* __restrict__ Ql,
            const u16* __restrict__ Pht, const u16* __restrict__ Plt,
            const float* __restrict__ temp, const int* __restrict__ total_p,
            float* __restrict__ m_part, float* __restrict__ z_part,
            float* __restrict__ Lg) {
  int bid = blockIdx.x;
  int kt = (bid & 7) * 8 + ((bid >> 3) & 7);
  int rt = bid >> 6;
  int total = total_p[0];
  int row0 = rt * BM;
  if (row0 >= total) return;
  int tid = threadIdx.x;
  int wid = tid >> 6, lane = tid & 63;
  int wm = wid >> 1, wn = wid & 1;
  int fr = lane & 15, fq = lane >> 4;
  int psl = fq ^ ((fr >> 1) & 3);

  __shared__ u16 Ah[2][BM*32], Al[2][BM*32], Bh[2][BN*32], Bl[2][BN*32];
  __shared__ float mloc[2][BM], zloc[2][BM];

  float invT = 1.0f / temp[0];

  int c0 = wid*128 + lane, c1 = c0 + 64;
  int rl0 = c0 >> 2, rl1 = c1 >> 2;
  int sl0 = (c0 & 3) ^ ((rl0 >> 1) & 3);
  int sl1 = (c1 & 3) ^ ((rl1 >> 1) & 3);
  int gr0 = min(row0 + rl0, total - 1);
  int gr1 = min(row0 + rl1, total - 1);
  const u16* qh0 = Qh + (size_t)gr0*ND + sl0*8;
  const u16* qh1 = Qh + (size_t)gr1*ND + sl1*8;
  const u16* ql0 = Ql + (size_t)gr0*ND + sl0*8;
  const u16* ql1 = Ql + (size_t)gr1*ND + sl1*8;

  auto stage = [&](int bf, int dt) {
    int dq = dt * 32;
    size_t pofs = (size_t)kt*NDSTEP*4096 + (size_t)dt*4096;
    const u16* ph = Pht + pofs;
    const u16* pl = Plt + pofs;
    int w = wid*1024;
    gload16(qh0 + dq, &Ah[bf][w]);          gload16(qh1 + dq, &Ah[bf][w+512]);
    gload16(ql0 + dq, &Al[bf][w]);          gload16(ql1 + dq, &Al[bf][w+512]);
    gload16(ph + (size_t)c0*8, &Bh[bf][w]); gload16(ph + (size_t)c1*8, &Bh[bf][w+512]);
    gload16(pl + (size_t)c0*8, &Bl[bf][w]); gload16(pl + (size_t)c1*8, &Bl[bf][w+512]);
  };

  stage(0, 0);
  __syncthreads();
  int buf = 0;

  f32x4 acc[4][4];
#pragma unroll
  for (int i = 0; i < 4; ++i)
#pragma unroll
    for (int j = 0; j < 4; ++j) acc[i][j] = f32x4{0.f, 0.f, 0.f, 0.f};

  for (int dt = 0; dt < NDSTEP; ++dt) {
    if (dt < NDSTEP-1) stage(buf^1, dt+1);
    mfma_step(Ah[buf], Al[buf], Bh[buf], Bl[buf], wm, wn, fr, psl, acc);
    __syncthreads();
    buf ^= 1;
  }

#pragma unroll
  for (int i = 0; i < 4; ++i)
#pragma unroll
    for (int j = 0; j < 4; ++j) acc[i][j] *= invT;

  // per-row (max, sumexp) over this 128-wide k-tile
#pragma unroll
  for (int mi = 0; mi < 4; ++mi)
#pragma unroll
    for (int r = 0; r < 4; ++r) {
      float vm = -INFINITY;
#pragma unroll
      for (int ni = 0; ni < 4; ++ni) vm = fmaxf(vm, acc[mi][ni][r]);
      vm = fmaxf(vm, __shfl_xor(vm, 1));
      vm = fmaxf(vm, __shfl_xor(vm, 2));
      vm = fmaxf(vm, __shfl_xor(vm, 4));
      vm = fmaxf(vm, __shfl_xor(vm, 8));
      float s = 0.f;
#pragma unroll
      for (int ni = 0; ni < 4; ++ni) s += __expf(acc[mi][ni][r] - vm);
      s += __shfl_xor(s, 1); s += __shfl_xor(s, 2);
      s += __shfl_xor(s, 4); s += __shfl_xor(s, 8);
      if (fr == 0) {
        int slot = wm*64 + mi*16 + fq*4 + r;
        mloc[wn][slot] = vm; zloc[wn][slot] = s;
      }
    }
  __syncthreads();
  if (tid < BM && row0 + tid < total) {
    float m0 = mloc[0][tid], m1 = mloc[1][tid];
    float z0 = zloc[0][tid], z1 = zloc[1][tid];
    float mw = fmaxf(m0, m1);
    float zw = z0 * __expf(m0 - mw) + z1 * __expf(m1 - mw);
    m_part[(size_t)kt * NM + row0 + tid] = mw;
    z_part[(size_t)kt * NM + row0 + tid] = zw;
  }

  // store fp32 logits (rows beyond total hold duplicates; never read)
  int k0 = kt * BN;
#pragma unroll
  for (int mi = 0; mi < 4; ++mi) {
    int row = row0 + wm*64 + mi*16 + fq*4;
#pragma unroll
    for (int r = 0; r < 4; ++r) {
      float* dst = Lg + (size_t)(row + r) * NK + k0 + wn*64 + fr;
#pragma unroll
      for (int ni = 0; ni < 4; ++ni) dst[ni*16] = acc[mi][ni][r];
    }
  }
}

// combines: c[j] = m_j + log Z_j from 64 k-tile partials.
__global__ __launch_bounds__(256)
void combines(const float* __restrict__ m_part, const float* __restrict__ z_part,
              const int* __restrict__ total_p, float* __restrict__ c_c) {
  int j = blockIdx.x * 256 + threadIdx.x;
  if (j >= total_p[0]) return;
  float m = -INFINITY;
  for (int k = 0; k < 64; ++k) m = fmaxf(m, m_part[(size_t)k*NM + j]);
  float z = 0.f;
  for (int k = 0; k < 64; ++k)
    z += z_part[(size_t)k*NM + j] * __expf(m_part[(size_t)k*NM + j] - m);
  c_c[j] = m + __logf(z);
}

// pass2s: per (b, kt) stream logits, col-max of (x - c), exp at the end.
__global__ __launch_bounds__(256)
void pass2s(const float* __restrict__ Lg, const float* __restrict__ c_c,
            const int* __restrict__ cntb, const int* __restrict__ offb,
            float* __restrict__ out) {
  int bid = blockIdx.x;              // 2048 = 64 kt x 32 b
  int kt = bid & 63, b = bid >> 6;
  int cb = cntb[b], ob = offb[b];
  int tid = threadIdx.x;
  int k0 = kt * BN;

  __shared__ float cs[NL];
  __shared__ float red[8][BN];

  for (int j = tid; j < cb; j += 256) cs[j] = c_c[ob + j];
  __syncthreads();

  int col4 = (tid & 31) * 4;
  int rg = tid >> 5;                  // 8 row groups
  float4 v = make_float4(-INFINITY, -INFINITY, -INFINITY, -INFINITY);
  for (int j = rg; j < cb; j += 8) {
    float4 x = *(const float4*)&Lg[(size_t)(ob + j) * NK + k0 + col4];
    float c = cs[j];
    v.x = fmaxf(v.x, x.x - c);
    v.y = fmaxf(v.y, x.y - c);
    v.z = fmaxf(v.z, x.z - c);
    v.w = fmaxf(v.w, x.w - c);
  }
  *(float4*)&red[rg][col4] = v;
  __syncthreads();
  if (tid < BN) {
    float m = red[0][tid];
#pragma unroll
    for (int g = 1; g < 8; ++g) m = fmaxf(m, red[g][tid]);
    out[(size_t)b*NK + k0 + tid] = (cb > 0) ? __expf(m) : 0.f;
  }
}

// ===========================================================================
// FALLBACK PATH (R5, proven): online pass1 over k-slices + recompute pass2.
// ===========================================================================

__global__ __launch_bounds__(256, 2)
void pass1_fb(const u16* __restrict__ Qh, const u16* __restrict__ Ql,
              const u16* __restrict__ Pht, const u16* __restrict__ Plt,
              const float* __restrict__ temp, const int* __restrict__ total_p,
              float* __restrict__ m_part, float* __restrict__ z_part) {
  int bid = blockIdx.x;
  int kh = bid & 15, rt = bid >> 4;
  int total = total_p[0];
  int row0 = rt * BM;
  if (row0 >= total) return;
  int tid = threadIdx.x;
  int wid = tid >> 6, lane = tid & 63;
  int wm = wid >> 1, wn = wid & 1;
  int fr = lane & 15, fq = lane >> 4;
  int psl = fq ^ ((fr >> 1) & 3);

  __shared__ u16 Ah[2][BM*32], Al[2][BM*32], Bh[2][BN*32], Bl[2][BN*32];
  __shared__ float mloc[2][BM], zloc[2][BM];

  float invT = 1.0f / temp[0];
  int c0 = wid*128 + lane, c1 = c0 + 64;
  int rl0 = c0 >> 2, rl1 = c1 >> 2;
  int sl0 = (c0 & 3) ^ ((rl0 >> 1) & 3);
  int sl1 = (c1 & 3) ^ ((rl1 >> 1) & 3);
  int gr0 = min(row0 + rl0, total - 1);
  int gr1 = min(row0 + rl1, total - 1);
  const u16* qh0 = Qh + (size_t)gr0*ND + sl0*8;
  const u16* qh1 = Qh + (size_t)gr1*ND + sl1*8;
  const u16* ql0 = Ql + (size_t)gr0*ND + sl0*8;
  const u16* ql1 = Ql + (size_t)gr1*ND + sl1*8;

  auto stage = [&](int bf, int ktg, int dt) {
    int dq = dt * 32;
    size_t pofs = (size_t)ktg*NDSTEP*4096 + (size_t)dt*4096;
    const u16* ph = Pht + pofs;
    const u16* pl = Plt + pofs;
    int w = wid*1024;
    gload16(qh0 + dq, &Ah[bf][w]);          gload16(qh1 + dq, &Ah[bf][w+512]);
    gload16(ql0 + dq, &Al[bf][w]);          gload16(ql1 + dq, &Al[bf][w+512]);
    gload16(ph + (size_t)c0*8, &Bh[bf][w]); gload16(ph + (size_t)c1*8, &Bh[bf][w+512]);
    gload16(pl + (size_t)c0*8, &Bl[bf][w]); gload16(pl + (size_t)c1*8, &Bl[bf][w+512]);
  };

  float mrun = -INFINITY, zrun = 0.f;
  int ktg0 = kh * (KSLICE/BN);

  stage(0, ktg0, 0);
  __syncthreads();
  int buf = 0;

  for (int kt = 0; kt < KSLICE/BN; ++kt) {
    f32x4 acc[4][4];
#pragma unroll
    for (int i = 0; i < 4; ++i)
#pragma unroll
      for (int j = 0; j < 4; ++j) acc[i][j] = f32x4{0.f, 0.f, 0.f, 0.f};

    for (int dt = 0; dt < NDSTEP; ++dt) {
      if (dt < NDSTEP-1)            stage(buf^1, ktg0 + kt, dt+1);
      else if (kt < KSLICE/BN - 1)  stage(buf^1, ktg0 + kt + 1, 0);
      mfma_step(Ah[buf], Al[buf], Bh[buf], Bl[buf], wm, wn, fr, psl, acc);
      __syncthreads();
      buf ^= 1;
    }

#pragma unroll
    for (int i = 0; i < 4; ++i)
#pragma unroll
      for (int j = 0; j < 4; ++j) acc[i][j] *= invT;

#pragma unroll
    for (int mi = 0; mi < 4; ++mi)
#pragma unroll
      for (int r = 0; r < 4; ++r) {
        float vm = -INFINITY;
#pragma unroll
        for (int ni = 0; ni < 4; ++ni) vm = fmaxf(vm, acc[mi][ni][r]);
        vm = fmaxf(vm, __shfl_xor(vm, 1));
        vm = fmaxf(vm, __shfl_xor(vm, 2));
        vm = fmaxf(vm, __shfl_xor(vm, 4));
        vm = fmaxf(vm, __shfl_xor(vm, 8));
        float s = 0.f;
#pragma unroll
        for (int ni = 0; ni < 4; ++ni) s += __expf(acc[mi][ni][r] - vm);
        s += __shfl_xor(s, 1); s += __shfl_xor(s, 2);
        s += __shfl_xor(s, 4); s += __shfl_xor(s, 8);
        if (fr == 0) {
          int slot = wm*64 + mi*16 + fq*4 + r;
          mloc[wn][slot] = vm; zloc[wn][slot] = s;
        }
      }
    __syncthreads();
    if (tid < BM) {
      float m0 = mloc[0][tid], m1 = mloc[1][tid];
      float z0 = zloc[0][tid], z1 = zloc[1][tid];
      float mw = fmaxf(m0, m1);
      float zw = z0 * __expf(m0 - mw) + z1 * __expf(m1 - mw);
      float mn = fmaxf(mrun, mw);
      zrun = zrun * __expf(mrun - mn) + zw * __expf(mw - mn);
      mrun = mn;
    }
    __syncthreads();
  }

  if (tid < BM && row0 + tid < total) {
    m_part[(size_t)kh * NM + row0 + tid] = mrun;
    z_part[(size_t)kh * NM + row0 + tid] = zrun;
  }
}

__global__ __launch_bounds__(256)
void combine_fb(const float* __restrict__ m_part, const float* __restrict__ z_part,
                const int* __restrict__ total_p,
                float* __restrict__ m_c, float* __restrict__ iz_c) {
  int j = blockIdx.x * 256 + threadIdx.x;
  if (j >= total_p[0]) return;
  float m = -INFINITY;
#pragma unroll
  for (int k = 0; k < KSPLIT; ++k) m = fmaxf(m, m_part[(size_t)k*NM + j]);
  float z = 0.f;
#pragma unroll
  for (int k = 0; k < KSPLIT; ++k)
    z += z_part[(size_t)k*NM + j] * __expf(m_part[(size_t)k*NM + j] - m);
  m_c[j] = m;
  iz_c[j] = 1.0f / z;
}

__global__ __launch_bounds__(256, 2)
void pass2_fb(const u16* __restrict__ Qh, const u16* __restrict__ Ql,
              const u16* __restrict__ Pht, const u16* __restrict__ Plt,
              const float* __restrict__ temp,
              const int* __restrict__ cntb, const int* __restrict__ offb,
              const float* __restrict__ m_c, const float* __restrict__ iz_c,
              float* __restrict__ out) {
  int bid = blockIdx.x;
  int kt = (bid & 7) * 8 + ((bid >> 3) & 7);
  int b = bid >> 6;
  int cb = cntb[b], ob = offb[b];
  int tid = threadIdx.x;
  if (cb == 0) { if (tid < BN) out[(size_t)b*NK + kt*BN + tid] = 0.f; return; }

  int wid = tid >> 6, lane = tid & 63;
  int wm = wid >> 1, wn = wid & 1;
  int fr = lane & 15, fq = lane >> 4;
  int psl = fq ^ ((fr >> 1) & 3);

  __shared__ u16 Ah[2][BM*32], Al[2][BM*32], Bh[2][BN*32], Bl[2][BN*32];
  __shared__ float mrow[BM], izrow[BM];
  __shared__ float red[2][BN];

  float invT = 1.0f / temp[0];
  int c0 = wid*128 + lane, c1 = c0 + 64;
  int rl0 = c0 >> 2, rl1 = c1 >> 2;
  int sl0 = (c0 & 3) ^ ((rl0 >> 1) & 3);
  int sl1 = (c1 & 3) ^ ((rl1 >> 1) & 3);

  const u16 *qh0, *qh1, *ql0, *ql1;
  auto setq = [&](int t0) {
    int g0 = ob + min(t0 + rl0, cb - 1);
    int g1 = ob + min(t0 + rl1, cb - 1);
    qh0 = Qh + (size_t)g0*ND + sl0*8;
    qh1 = Qh + (size_t)g1*ND + sl1*8;
    ql0 = Ql + (size_t)g0*ND + sl0*8;
    ql1 = Ql + (size_t)g1*ND + sl1*8;
  };
  auto stage = [&](int bf, int dt) {
    int dq = dt * 32;
    size_t pofs = (size_t)kt*NDSTEP*4096 + (size_t)dt*4096;
    const u16* ph = Pht + pofs;
    const u16* pl = Plt + pofs;
    int w = wid*1024;
    gload16(qh0 + dq, &Ah[bf][w]);          gload16(qh1 + dq, &Ah[bf][w+512]);
    gload16(ql0 + dq, &Al[bf][w]);          gload16(ql1 + dq, &Al[bf][w+512]);
    gload16(ph + (size_t)c0*8, &Bh[bf][w]); gload16(ph + (size_t)c1*8, &Bh[bf][w+512]);
    gload16(pl + (size_t)c0*8, &Bl[bf][w]); gload16(pl + (size_t)c1*8, &Bl[bf][w+512]);
  };

  float rc[4] = {0.f, 0.f, 0.f, 0.f};

  setq(0);
  stage(0, 0);
  __syncthreads();
  int buf = 0;

  for (int t0 = 0; t0 < cb; t0 += BM) {
    if (tid < BM) {
      int j = min(t0 + tid, cb - 1);
      mrow[tid] = m_c[ob + j];
      izrow[tid] = (t0 + tid < cb) ? iz_c[ob + j] : 0.f;
    }

    f32x4 acc[4][4];
#pragma unroll
    for (int i = 0; i < 4; ++i)
#pragma unroll
      for (int j = 0; j < 4; ++j) acc[i][j] = f32x4{0.f, 0.f, 0.f, 0.f};

    for (int dt = 0; dt < NDSTEP; ++dt) {
      if (dt < NDSTEP-1) {
        stage(buf^1, dt+1);
      } else if (t0 + BM < cb) {
        setq(t0 + BM);
        stage(buf^1, 0);
      }
      mfma_step(Ah[buf], Al[buf], Bh[buf], Bl[buf], wm, wn, fr, psl, acc);
      __syncthreads();
      buf ^= 1;
    }

#pragma unroll
    for (int mi = 0; mi < 4; ++mi)
#pragma unroll
      for (int r = 0; r < 4; ++r) {
        int slot = wm*64 + mi*16 + fq*4 + r;
        float mv = mrow[slot], izv = izrow[slot];
#pragma unroll
        for (int ni = 0; ni < 4; ++ni)
          rc[ni] = fmaxf(rc[ni], __expf(acc[mi][ni][r]*invT - mv) * izv);
      }
    __syncthreads();
  }

#pragma unroll
  for (int ni = 0; ni < 4; ++ni) {
    rc[ni] = fmaxf(rc[ni], __shfl_xor(rc[ni], 16));
    rc[ni] = fmaxf(rc[ni], __shfl_xor(rc[ni], 32));
  }
  if (fq == 0) {
#pragma unroll
    for (int ni = 0; ni < 4; ++ni) red[wm][wn*64 + ni*16 + fr] = rc[ni];
  }
  __syncthreads();
  if (tid < BN) out[(size_t)b*NK + kt*BN + tid] = fmaxf(red[0][tid], red[1][tid]);
}

// ---------------------------------------------------------------------------
// L2-normalize each batch row (length NK), torch-eps clamp.
// ---------------------------------------------------------------------------
__global__ __launch_bounds__(256)
void normalize_rows(float* __restrict__ out) {
  int b = blockIdx.x;
  int tid = threadIdx.x;
  float* row = out + (size_t)b * NK;
  float ss = 0.f;
  for (int i = tid; i < NK; i += 256) { float v = row[i]; ss = fmaf(v, v, ss); }
#pragma unroll
  for (int o = 1; o < 64; o <<= 1) ss += __shfl_xor(ss, o);
  __shared__ float wsum[4];
  int lane = tid & 63, wv = tid >> 6;
  if (lane == 0) wsum[wv] = ss;
  __syncthreads();
  float tot = wsum[0] + wsum[1] + wsum[2] + wsum[3];
  float inv = 1.0f / fmaxf(sqrtf(tot), 1e-12f);
  for (int i = tid; i < NK; i += 256) row[i] *= inv;
}

// ---------------------------------------------------------------------------
extern "C" void kernel_launch(void* const* d_in, const int* in_sizes, int n_in,
                              void* d_out, int out_size, void* d_ws, size_t ws_size,
                              hipStream_t stream) {
  const float* q    = (const float*)d_in[0];
  const float* p    = (const float*)d_in[1];
  const float* temp = (const float*)d_in[2];
  const int*   mask = (const int*)d_in[3];
  float* out = (float*)d_out;
  float* wsf = (float*)d_ws;

  // ---- streaming layout (float offsets) ----
  // m_part[64*NM] | z_part[64*NM] | c_c[NM] | vg[NM int] | cntb,offb,total |
  // pad->128 | Qh,Ql (NM*ND u16 each) | Pht,Plt (NK*ND u16 each) | Lg[NM*NK]
  const size_t S_MPART = 0;
  const size_t S_ZPART = S_MPART + 64ull*NM;
  const size_t S_CC    = S_ZPART + 64ull*NM;
  const size_t S_VG    = S_CC + NM;
  const size_t S_CNT   = S_VG + NM;           // ints from here
  const size_t S_BF    = ((S_CNT + 2*NB + 1 + 127) / 128) * 128;
  const size_t S_QHL   = (size_t)NM*ND;       // u16 count per Q array
  const size_t S_PHL   = (size_t)NK*ND;       // u16 count per P array
  const size_t S_LG    = S_BF + (2*S_QHL + 2*S_PHL) / 2;   // float offset
  const size_t S_END   = S_LG + (size_t)NM*NK;
  const size_t NEED_STREAM = S_END * 4;

  if (ws_size >= NEED_STREAM) {
    float* m_part = wsf + S_MPART;
    float* z_part = wsf + S_ZPART;
    float* c_c    = wsf + S_CC;
    int*   vg     = (int*)(wsf + S_VG);
    int*   cntb   = (int*)(wsf + S_CNT);
    int*   offb   = cntb + NB;
    int*   total  = offb + NB;
    u16*   Qh     = (u16*)(wsf + S_BF);
    u16*   Ql     = Qh + S_QHL;
    u16*   Pht    = Ql + S_QHL;
    u16*   Plt    = Pht + S_PHL;
    float* Lg     = wsf + S_LG;

    compact_all<<<1, 512, 0, stream>>>(mask, vg, cntb, offb, total);
    convert_q<<<(NM*(ND/8))/256, 256, 0, stream>>>(q, vg, total, Qh, Ql);
    convert_p<<<(64*NDSTEP*512)/256, 256, 0, stream>>>(p, Pht, Plt);
    pass1s<<<(NM/BM)*64, 256, 0, stream>>>(Qh, Ql, Pht, Plt, temp, total,
                                           m_part, z_part, Lg);
    combines<<<NM/256, 256, 0, stream>>>(m_part, z_part, total, c_c);
    pass2s<<<64*NB, 256, 0, stream>>>(Lg, c_c, cntb, offb, out);
    normalize_rows<<<NB, 256, 0, stream>>>(out);
  } else {
    // ---- fallback: exact R5 layout & kernels ----
    float* m_c    = wsf;
    float* iz_c   = wsf + NM;
    float* m_part = wsf + 2*NM;
    float* z_part = wsf + 2*NM + (size_t)KSPLIT*NM;
    int*   vg     = (int*)(wsf + 2*NM + (size_t)2*KSPLIT*NM);
    int*   cntb   = vg + NM;
    int*   offb   = cntb + NB;
    int*   total  = offb + NB;
    u16*   Qh     = (u16*)(wsf + (size_t)(2 + 2*KSPLIT + 1)*NM + 128);
    u16*   Ql     = Qh + (size_t)NM*ND;
    u16*   Pht    = Ql + (size_t)NM*ND;
    u16*   Plt    = Pht + (size_t)NK*ND;

    compact_all<<<1, 512, 0, stream>>>(mask, vg, cntb, offb, total);
    convert_q<<<(NM*(ND/8))/256, 256, 0, stream>>>(q, vg, total, Qh, Ql);
    convert_p<<<(64*NDSTEP*512)/256, 256, 0, stream>>>(p, Pht, Plt);
    pass1_fb<<<(NM/BM)*KSPLIT, 256, 0, stream>>>(Qh, Ql, Pht, Plt, temp, total,
                                                 m_part, z_part);
    combine_fb<<<NM/256, 256, 0, stream>>>(m_part, z_part, total, m_c, iz_c);
    pass2_fb<<<64*NB, 256, 0, stream>>>(Qh, Ql, Pht, Plt, temp, cntb, offb,
                                        m_c, iz_c, out);
    normalize_rows<<<NB, 256, 0, stream>>>(out);
  }
}

// Round 9
// 580.125 us; speedup vs baseline: 1.3106x; 1.3106x over previous
//
#include <hip/hip_runtime.h>
#include <cmath>

#define NB 32
#define NL 512
#define ND 768
#define NK 8192
#define NM (NB*NL)        // 16384 max (padded) rows
#define BM 128
#define BN 128
#define NDSTEP (ND/32)    // 24 d-steps of BK=32
#define KSPLIT 16
#define KSLICE (NK/KSPLIT)   // fallback path: 512-wide k-slices

typedef __attribute__((ext_vector_type(8))) short bf16x8;
typedef __attribute__((ext_vector_type(4))) float f32x4;
typedef __fp16 fp16x2 __attribute__((ext_vector_type(2)));
typedef unsigned short u16;
typedef unsigned int u32;

// async global->LDS, 16B per lane. dest must be wave-uniform; HW adds lane*16.
__device__ __forceinline__ void gload16(const void* g, void* s) {
  __builtin_amdgcn_global_load_lds(
      (const __attribute__((address_space(1))) char*)g,
      (__attribute__((address_space(3))) char*)s, 16, 0, 0);
}

// split fp32 pair into hi/lo bf16 pairs (packed)
__device__ __forceinline__ void split_pk(float x0, float x1, unsigned &h, unsigned &l) {
  unsigned hp;
  asm("v_cvt_pk_bf16_f32 %0, %1, %2" : "=v"(hp) : "v"(x0), "v"(x1));
  union { unsigned u; float f; } f0, f1;
  f0.u = hp << 16;
  f1.u = hp & 0xffff0000u;
  unsigned lp;
  float r0 = x0 - f0.f, r1 = x1 - f1.f;
  asm("v_cvt_pk_bf16_f32 %0, %1, %2" : "=v"(lp) : "v"(r0), "v"(r1));
  h = hp; l = lp;
}

__device__ __forceinline__ unsigned pkhalf(float a, float b) {
  union { fp16x2 h; unsigned u; } c;
  c.h = __builtin_amdgcn_cvt_pkrtz(a, b);
  return c.u;
}

// One BK=32 step: 16 ds_read_b128 + 48 MFMAs (3-product split-bf16).
__device__ __forceinline__ void mfma_step(const u16* Ah, const u16* Al,
                                          const u16* Bh, const u16* Bl,
                                          int wm, int wn, int fr, int psl,
                                          f32x4 acc[4][4]) {
  bf16x8 aH[4], aL[4], bH[4], bL[4];
#pragma unroll
  for (int i = 0; i < 4; ++i) {
    int ar = (wm*64 + i*16 + fr)*32 + psl*8;
    int br = (wn*64 + i*16 + fr)*32 + psl*8;
    aH[i] = *(const bf16x8*)&Ah[ar];
    aL[i] = *(const bf16x8*)&Al[ar];
    bH[i] = *(const bf16x8*)&Bh[br];
    bL[i] = *(const bf16x8*)&Bl[br];
  }
  __builtin_amdgcn_s_setprio(1);
#pragma unroll
  for (int mi = 0; mi < 4; ++mi)
#pragma unroll
    for (int ni = 0; ni < 4; ++ni) {
      acc[mi][ni] = __builtin_amdgcn_mfma_f32_16x16x32_bf16(aH[mi], bH[ni], acc[mi][ni], 0, 0, 0);
      acc[mi][ni] = __builtin_amdgcn_mfma_f32_16x16x32_bf16(aH[mi], bL[ni], acc[mi][ni], 0, 0, 0);
      acc[mi][ni] = __builtin_amdgcn_mfma_f32_16x16x32_bf16(aL[mi], bH[ni], acc[mi][ni], 0, 0, 0);
    }
  __builtin_amdgcn_s_setprio(0);
}

// ---------------------------------------------------------------------------
// Compaction (simple, batch-major) — fallback path.
// ---------------------------------------------------------------------------
__global__ __launch_bounds__(512)
void compact_all(const int* __restrict__ mask, int* __restrict__ vg,
                 int* __restrict__ cntb, int* __restrict__ offb,
                 int* __restrict__ total) {
  __shared__ int wcnt[8], woff[8];
  __shared__ int base;
  int t = threadIdx.x;
  if (t == 0) base = 0;
  __syncthreads();
  for (int b = 0; b < NB; ++b) {
    int v = (mask[b*NL + t] != 0) ? 1 : 0;
    unsigned long long bal = __ballot(v);
    int lane = t & 63, wv = t >> 6;
    int pos = __popcll(bal & ((1ull << lane) - 1ull));
    if (lane == 0) wcnt[wv] = __popcll(bal);
    __syncthreads();
    if (t == 0) {
      int s = 0;
#pragma unroll
      for (int w = 0; w < 8; ++w) { woff[w] = s; s += wcnt[w]; }
      cntb[b] = s; offb[b] = base;
    }
    __syncthreads();
    if (v) vg[base + woff[wv] + pos] = b*NL + t;
    __syncthreads();
    if (t == 0) base += cntb[b];
    __syncthreads();
  }
  if (t == 0) total[0] = base;
}

// ---------------------------------------------------------------------------
// Padded compaction: each batch's rows padded to a multiple of 128 with
// duplicates of its last valid row (benign under col-max). Streaming path.
// ---------------------------------------------------------------------------
__global__ __launch_bounds__(512)
void compact_pad(const int* __restrict__ mask, int* __restrict__ vg,
                 int* __restrict__ cntp, int* __restrict__ offp,
                 int* __restrict__ total) {
  __shared__ int wcnt[8], woff[8];
  __shared__ int base, s_sh, cnp_sh;
  int t = threadIdx.x;
  if (t == 0) base = 0;
  __syncthreads();
  for (int b = 0; b < NB; ++b) {
    int v = (mask[b*NL + t] != 0) ? 1 : 0;
    unsigned long long bal = __ballot(v);
    int lane = t & 63, wv = t >> 6;
    int pos = __popcll(bal & ((1ull << lane) - 1ull));
    if (lane == 0) wcnt[wv] = __popcll(bal);
    __syncthreads();
    if (t == 0) {
      int s = 0;
#pragma unroll
      for (int w = 0; w < 8; ++w) { woff[w] = s; s += wcnt[w]; }
      s_sh = s;
      cnp_sh = (s > 0) ? ((s + 127) & ~127) : 0;
      cntp[b] = cnp_sh; offp[b] = base;
    }
    __syncthreads();
    if (v) vg[base + woff[wv] + pos] = b*NL + t;
    __syncthreads();                        // valid writes visible
    if (t >= s_sh && t < cnp_sh) vg[base + t] = vg[base + s_sh - 1];
    __syncthreads();
    if (t == 0) base += cnp_sh;
    __syncthreads();
  }
  if (t == 0) total[0] = base;
}

// ---------------------------------------------------------------------------
// Convert Q -> compacted-row-major bf16 hi/lo.
// ---------------------------------------------------------------------------
__global__ __launch_bounds__(256)
void convert_q(const float* __restrict__ q, const int* __restrict__ vg,
               const int* __restrict__ total_p,
               u16* __restrict__ Qh, u16* __restrict__ Ql) {
  int total = total_p[0];
  int cid = blockIdx.x * 256 + threadIdx.x;       // chunk of 8 elements
  int row = cid / (ND/8), c = cid % (ND/8);
  if (row >= total) return;
  const float* src = q + (size_t)vg[row] * ND + c*8;
  float4 v0 = ((const float4*)src)[0], v1 = ((const float4*)src)[1];
  unsigned h[4], l[4];
  split_pk(v0.x, v0.y, h[0], l[0]); split_pk(v0.z, v0.w, h[1], l[1]);
  split_pk(v1.x, v1.y, h[2], l[2]); split_pk(v1.z, v1.w, h[3], l[3]);
  size_t o = (size_t)row * ND + c*8;
  *(uint4*)(Qh + o) = make_uint4(h[0], h[1], h[2], h[3]);
  *(uint4*)(Ql + o) = make_uint4(l[0], l[1], l[2], l[3]);
}

// ---------------------------------------------------------------------------
// Convert P -> tiled + pre-swizzled bf16 hi/lo.
// ---------------------------------------------------------------------------
__global__ __launch_bounds__(256)
void convert_p(const float* __restrict__ p,
               u16* __restrict__ Pht, u16* __restrict__ Plt) {
  int cid = blockIdx.x * 256 + threadIdx.x;        // 64*24*512 chunks
  int kt = cid / (NDSTEP*512);
  int rem = cid % (NDSTEP*512);
  int dt = rem / 512, c = rem % 512;
  int r = c >> 2, sp = c & 3;
  int sl = sp ^ ((r >> 1) & 3);
  const float* src = p + (size_t)(kt*128 + r) * ND + dt*32 + sl*8;
  float4 v0 = ((const float4*)src)[0], v1 = ((const float4*)src)[1];
  unsigned h[4], l[4];
  split_pk(v0.x, v0.y, h[0], l[0]); split_pk(v0.z, v0.w, h[1], l[1]);
  split_pk(v1.x, v1.y, h[2], l[2]); split_pk(v1.z, v1.w, h[3], l[3]);
  size_t o = (size_t)cid * 8;
  *(uint4*)(Pht + o) = make_uint4(h[0], h[1], h[2], h[3]);
  *(uint4*)(Plt + o) = make_uint4(l[0], l[1], l[2], l[3]);
}

// ===========================================================================
// STREAMING PATH (chunked): pass1s GEMM-tile -> u=x/T - m_tile (fp16, packed
// MFMA-order) + per-(kt,row) m/Z partials; combines -> c = m + logZ;
// pass2s streams u, accumulates col-max exponent into sacc.
// ===========================================================================

__global__ __launch_bounds__(256, 2)
void pass1s(const u16* __restrict__ Qh, const u16* __restrict__ Ql,
            const u16* __restrict__ Pht, const u16* __restrict__ Plt,
            const float* __restrict__ temp, const int* __restrict__ total_p,
            int chunk_base, int chrows,
            float* __restrict__ m_part, float* __restrict__ z_part,
            u16* __restrict__ Lg) {
  int bid = blockIdx.x;
  int kt = (bid & 7) * 8 + ((bid >> 3) & 7);    // XCD-sliced k-tile
  int rt = bid >> 6;
  int row0 = chunk_base + rt * BM;
  if (row0 >= total_p[0]) return;               // tiles are 128-aligned
  int tid = threadIdx.x;
  int wid = tid >> 6, lane = tid & 63;
  int wm = wid >> 1, wn = wid & 1;
  int fr = lane & 15, fq = lane >> 4;
  int psl = fq ^ ((fr >> 1) & 3);

  __shared__ u16 Ah[2][BM*32], Al[2][BM*32], Bh[2][BN*32], Bl[2][BN*32];
  __shared__ float mloc[2][BM], zloc[2][BM];

  float invT = 1.0f / temp[0];

  int c0 = wid*128 + lane, c1 = c0 + 64;
  int rl0 = c0 >> 2, rl1 = c1 >> 2;
  int sl0 = (c0 & 3) ^ ((rl0 >> 1) & 3);
  int sl1 = (c1 & 3) ^ ((rl1 >> 1) & 3);
  const u16* qh0 = Qh + (size_t)(row0 + rl0)*ND + sl0*8;
  const u16* qh1 = Qh + (size_t)(row0 + rl1)*ND + sl1*8;
  const u16* ql0 = Ql + (size_t)(row0 + rl0)*ND + sl0*8;
  const u16* ql1 = Ql + (size_t)(row0 + rl1)*ND + sl1*8;

  auto stage = [&](int bf, int dt) {
    int dq = dt * 32;
    size_t pofs = (size_t)kt*NDSTEP*4096 + (size_t)dt*4096;
    const u16* ph = Pht + pofs;
    const u16* pl = Plt + pofs;
    int w = wid*1024;
    gload16(qh0 + dq, &Ah[bf][w]);          gload16(qh1 + dq, &Ah[bf][w+512]);
    gload16(ql0 + dq, &Al[bf][w]);          gload16(ql1 + dq, &Al[bf][w+512]);
    gload16(ph + (size_t)c0*8, &Bh[bf][w]); gload16(ph + (size_t)c1*8, &Bh[bf][w+512]);
    gload16(pl + (size_t)c0*8, &Bl[bf][w]); gload16(pl + (size_t)c1*8, &Bl[bf][w+512]);
  };

  stage(0, 0);
  __syncthreads();
  int buf = 0;

  f32x4 acc[4][4];
#pragma unroll
  for (int i = 0; i < 4; ++i)
#pragma unroll
    for (int j = 0; j < 4; ++j) acc[i][j] = f32x4{0.f, 0.f, 0.f, 0.f};

  for (int dt = 0; dt < NDSTEP; ++dt) {
    if (dt < NDSTEP-1) stage(buf^1, dt+1);
    mfma_step(Ah[buf], Al[buf], Bh[buf], Bl[buf], wm, wn, fr, psl, acc);
    __syncthreads();
    buf ^= 1;
  }

#pragma unroll
  for (int i = 0; i < 4; ++i)
#pragma unroll
    for (int j = 0; j < 4; ++j) acc[i][j] *= invT;

  // per-row (max, sumexp) over this 128-wide k-tile
#pragma unroll
  for (int mi = 0; mi < 4; ++mi)
#pragma unroll
    for (int r = 0; r < 4; ++r) {
      float vm = -INFINITY;
#pragma unroll
      for (int ni = 0; ni < 4; ++ni) vm = fmaxf(vm, acc[mi][ni][r]);
      vm = fmaxf(vm, __shfl_xor(vm, 1));
      vm = fmaxf(vm, __shfl_xor(vm, 2));
      vm = fmaxf(vm, __shfl_xor(vm, 4));
      vm = fmaxf(vm, __shfl_xor(vm, 8));
      float s = 0.f;
#pragma unroll
      for (int ni = 0; ni < 4; ++ni) s += __expf(acc[mi][ni][r] - vm);
      s += __shfl_xor(s, 1); s += __shfl_xor(s, 2);
      s += __shfl_xor(s, 4); s += __shfl_xor(s, 8);
      if (fr == 0) {
        int slot = wm*64 + mi*16 + fq*4 + r;
        mloc[wn][slot] = vm; zloc[wn][slot] = s;
      }
    }
  __syncthreads();

  int rlbase = row0 - chunk_base;
  if (tid < BM) {
    float m0 = mloc[0][tid], m1 = mloc[1][tid];
    float z0 = zloc[0][tid], z1 = zloc[1][tid];
    float mw = fmaxf(m0, m1);
    float zw = z0 * __expf(m0 - mw) + z1 * __expf(m1 - mw);
    m_part[(size_t)kt * chrows + rlbase + tid] = mw;
    z_part[(size_t)kt * chrows + rlbase + tid] = zw;
  }

  // packed fp16 store of u = x/T - m_tile(row), MFMA-order, wave-contiguous:
  // u32 index = wid*2048 + vq*256 + lane*4 + s, v=4vq+s, mi=v>>3, r=(v>>1)&3,
  // pr=v&1 (cols ni=2pr lo, 2pr+1 hi).
  int lt = rlbase >> 7;
  u32* tb = (u32*)Lg + ((size_t)(lt*64 + kt))*8192 + wid*2048 + lane*4;
#pragma unroll
  for (int vq = 0; vq < 8; ++vq) {
    u32 pk4[4];
#pragma unroll
    for (int s2 = 0; s2 < 4; ++s2) {
      int v = vq*4 + s2;
      int mi = v >> 3, r = (v >> 1) & 3, pr = v & 1;
      int slot = wm*64 + mi*16 + fq*4 + r;
      float mw = fmaxf(mloc[0][slot], mloc[1][slot]);
      pk4[s2] = pkhalf(acc[mi][2*pr][r] - mw, acc[mi][2*pr+1][r] - mw);
    }
    *(uint4*)(tb + vq*256) = make_uint4(pk4[0], pk4[1], pk4[2], pk4[3]);
  }
}

// combines: c_loc[j] = m_j + log Z_j over 64 k-tiles (chunk-local rows).
__global__ __launch_bounds__(256)
void combines(const float* __restrict__ m_part, const float* __restrict__ z_part,
              const int* __restrict__ total_p, int chunk_base, int chrows,
              float* __restrict__ c_loc) {
  int j = blockIdx.x * 256 + threadIdx.x;
  if (j >= chrows || chunk_base + j >= total_p[0]) return;
  float m = -INFINITY;
  for (int k = 0; k < 64; ++k) m = fmaxf(m, m_part[(size_t)k*chrows + j]);
  float z = 0.f;
  for (int k = 0; k < 64; ++k)
    z += z_part[(size_t)k*chrows + j] * __expf(m_part[(size_t)k*chrows + j] - m);
  c_loc[j] = m + __logf(z);
}

// pass2s: per (b,kt) accumulate col-max exponent over batch tiles in chunk.
__global__ __launch_bounds__(256)
void pass2s(const u16* __restrict__ Lg,
            const float* __restrict__ m_part, const float* __restrict__ c_loc,
            const int* __restrict__ cntp, const int* __restrict__ offp,
            int chunk_base, int chrows, int chunk,
            float* __restrict__ sacc) {
  int bid = blockIdx.x;                 // 2048 = 64 kt x 32 b
  int kt = bid & 63, b = bid >> 6;
  int tid = threadIdx.x;
  int wid = tid >> 6, lane = tid & 63;
  int wm = wid >> 1, wn = wid & 1;
  int fr = lane & 15, fq = lane >> 4;

  __shared__ float e_s[BM];
  __shared__ float red[2][BN];

  int gt0 = offp[b] >> 7, ntile = cntp[b] >> 7;
  int lt0 = chunk_base >> 7, ltn = chrows >> 7;

  float cmax[4] = {-INFINITY, -INFINITY, -INFINITY, -INFINITY};
  int any = 0;

  for (int g = gt0; g < gt0 + ntile; ++g) {
    int lt = g - lt0;
    if (lt < 0 || lt >= ltn) continue;       // uniform per block
    any = 1;
    if (tid < BM) {
      int rl = lt*128 + tid;
      e_s[tid] = m_part[(size_t)kt*chrows + rl] - c_loc[rl];
    }
    __syncthreads();
    const u32* tb = (const u32*)Lg + ((size_t)(lt*64 + kt))*8192 + wid*2048 + lane*4;
#pragma unroll
    for (int vq = 0; vq < 8; ++vq) {
      uint4 w4 = *(const uint4*)(tb + vq*256);
      u32 ws[4] = {w4.x, w4.y, w4.z, w4.w};
#pragma unroll
      for (int s2 = 0; s2 < 4; ++s2) {
        int v = vq*4 + s2;
        int mi = v >> 3, r = (v >> 1) & 3, pr = v & 1;
        int rowt = wm*64 + mi*16 + fq*4 + r;
        union { u32 u; fp16x2 h; } dc; dc.u = ws[s2];
        float e = e_s[rowt];
        cmax[2*pr]   = fmaxf(cmax[2*pr],   (float)dc.h[0] + e);
        cmax[2*pr+1] = fmaxf(cmax[2*pr+1], (float)dc.h[1] + e);
      }
    }
    __syncthreads();
  }

  // reduce over fq (rows) then over wm via LDS
#pragma unroll
  for (int ni = 0; ni < 4; ++ni) {
    cmax[ni] = fmaxf(cmax[ni], __shfl_xor(cmax[ni], 16));
    cmax[ni] = fmaxf(cmax[ni], __shfl_xor(cmax[ni], 32));
  }
  if (fq == 0) {
#pragma unroll
    for (int ni = 0; ni < 4; ++ni) red[wm][wn*64 + ni*16 + fr] = cmax[ni];
  }
  __syncthreads();
  if (tid < BN) {
    float v = any ? fmaxf(red[0][tid], red[1][tid]) : -INFINITY;
    size_t o = (size_t)b*NK + kt*BN + tid;
    if (chunk == 0)      sacc[o] = v;
    else if (any)        sacc[o] = fmaxf(sacc[o], v);
  }
}

// normalize_s: out = exp(sacc) / ||exp(sacc)||_2 per batch (torch eps clamp).
__global__ __launch_bounds__(256)
void normalize_s(const float* __restrict__ sacc, float* __restrict__ out) {
  int b = blockIdx.x, tid = threadIdx.x;
  float e[32]; float ss = 0.f;
#pragma unroll
  for (int i = 0; i < 32; ++i) {
    float v = __expf(sacc[(size_t)b*NK + i*256 + tid]);   // exp(-inf)=0
    e[i] = v; ss = fmaf(v, v, ss);
  }
#pragma unroll
  for (int o = 1; o < 64; o <<= 1) ss += __shfl_xor(ss, o);
  __shared__ float wsum[4];
  int lane = tid & 63, wv = tid >> 6;
  if (lane == 0) wsum[wv] = ss;
  __syncthreads();
  float tot = wsum[0] + wsum[1] + wsum[2] + wsum[3];
  float inv = 1.0f / fmaxf(sqrtf(tot), 1e-12f);
#pragma unroll
  for (int i = 0; i < 32; ++i) out[(size_t)b*NK + i*256 + tid] = e[i] * inv;
}

// ===========================================================================
// FALLBACK PATH (R5, proven): online pass1 over k-slices + recompute pass2.
// ===========================================================================

__global__ __launch_bounds__(256, 2)
void pass1_fb(const u16* __restrict__ Qh, const u16* __restrict__ Ql,
              const u16* __restrict__ Pht, const u16* __restrict__ Plt,
              const float* __restrict__ temp, const int* __restrict__ total_p,
              float* __restrict__ m_part, float* __restrict__ z_part) {
  int bid = blockIdx.x;
  int kh = bid & 15, rt = bid >> 4;
  int total = total_p[0];
  int row0 = rt * BM;
  if (row0 >= total) return;
  int tid = threadIdx.x;
  int wid = tid >> 6, lane = tid & 63;
  int wm = wid >> 1, wn = wid & 1;
  int fr = lane & 15, fq = lane >> 4;
  int psl = fq ^ ((fr >> 1) & 3);

  __shared__ u16 Ah[2][BM*32], Al[2][BM*32], Bh[2][BN*32], Bl[2][BN*32];
  __shared__ float mloc[2][BM], zloc[2][BM];

  float invT = 1.0f / temp[0];
  int c0 = wid*128 + lane, c1 = c0 + 64;
  int rl0 = c0 >> 2, rl1 = c1 >> 2;
  int sl0 = (c0 & 3) ^ ((rl0 >> 1) & 3);
  int sl1 = (c1 & 3) ^ ((rl1 >> 1) & 3);
  int gr0 = min(row0 + rl0, total - 1);
  int gr1 = min(row0 + rl1, total - 1);
  const u16* qh0 = Qh + (size_t)gr0*ND + sl0*8;
  const u16* qh1 = Qh + (size_t)gr1*ND + sl1*8;
  const u16* ql0 = Ql + (size_t)gr0*ND + sl0*8;
  const u16* ql1 = Ql + (size_t)gr1*ND + sl1*8;

  auto stage = [&](int bf, int ktg, int dt) {
    int dq = dt * 32;
    size_t pofs = (size_t)ktg*NDSTEP*4096 + (size_t)dt*4096;
    const u16* ph = Pht + pofs;
    const u16* pl = Plt + pofs;
    int w = wid*1024;
    gload16(qh0 + dq, &Ah[bf][w]);          gload16(qh1 + dq, &Ah[bf][w+512]);
    gload16(ql0 + dq, &Al[bf][w]);          gload16(ql1 + dq, &Al[bf][w+512]);
    gload16(ph + (size_t)c0*8, &Bh[bf][w]); gload16(ph + (size_t)c1*8, &Bh[bf][w+512]);
    gload16(pl + (size_t)c0*8, &Bl[bf][w]); gload16(pl + (size_t)c1*8, &Bl[bf][w+512]);
  };

  float mrun = -INFINITY, zrun = 0.f;
  int ktg0 = kh * (KSLICE/BN);

  stage(0, ktg0, 0);
  __syncthreads();
  int buf = 0;

  for (int kt = 0; kt < KSLICE/BN; ++kt) {
    f32x4 acc[4][4];
#pragma unroll
    for (int i = 0; i < 4; ++i)
#pragma unroll
      for (int j = 0; j < 4; ++j) acc[i][j] = f32x4{0.f, 0.f, 0.f, 0.f};

    for (int dt = 0; dt < NDSTEP; ++dt) {
      if (dt < NDSTEP-1)            stage(buf^1, ktg0 + kt, dt+1);
      else if (kt < KSLICE/BN - 1)  stage(buf^1, ktg0 + kt + 1, 0);
      mfma_step(Ah[buf], Al[buf], Bh[buf], Bl[buf], wm, wn, fr, psl, acc);
      __syncthreads();
      buf ^= 1;
    }

#pragma unroll
    for (int i = 0; i < 4; ++i)
#pragma unroll
      for (int j = 0; j < 4; ++j) acc[i][j] *= invT;

#pragma unroll
    for (int mi = 0; mi < 4; ++mi)
#pragma unroll
      for (int r = 0; r < 4; ++r) {
        float vm = -INFINITY;
#pragma unroll
        for (int ni = 0; ni < 4; ++ni) vm = fmaxf(vm, acc[mi][ni][r]);
        vm = fmaxf(vm, __shfl_xor(vm, 1));
        vm = fmaxf(vm, __shfl_xor(vm, 2));
        vm = fmaxf(vm, __shfl_xor(vm, 4));
        vm = fmaxf(vm, __shfl_xor(vm, 8));
        float s = 0.f;
#pragma unroll
        for (int ni = 0; ni < 4; ++ni) s += __expf(acc[mi][ni][r] - vm);
        s += __shfl_xor(s, 1); s += __shfl_xor(s, 2);
        s += __shfl_xor(s, 4); s += __shfl_xor(s, 8);
        if (fr == 0) {
          int slot = wm*64 + mi*16 + fq*4 + r;
          mloc[wn][slot] = vm; zloc[wn][slot] = s;
        }
      }
    __syncthreads();
    if (tid < BM) {
      float m0 = mloc[0][tid], m1 = mloc[1][tid];
      float z0 = zloc[0][tid], z1 = zloc[1][tid];
      float mw = fmaxf(m0, m1);
      float zw = z0 * __expf(m0 - mw) + z1 * __expf(m1 - mw);
      float mn = fmaxf(mrun, mw);
      zrun = zrun * __expf(mrun - mn) + zw * __expf(mw - mn);
      mrun = mn;
    }
    __syncthreads();
  }

  if (tid < BM && row0 + tid < total) {
    m_part[(size_t)kh * NM + row0 + tid] = mrun;
    z_part[(size_t)kh * NM + row0 + tid] = zrun;
  }
}

__global__ __launch_bounds__(256)
void combine_fb(const float* __restrict__ m_part, const float* __restrict__ z_part,
                const int* __restrict__ total_p,
                float* __restrict__ m_c, float* __restrict__ iz_c) {
  int j = blockIdx.x * 256 + threadIdx.x;
  if (j >= total_p[0]) return;
  float m = -INFINITY;
#pragma unroll
  for (int k = 0; k < KSPLIT; ++k) m = fmaxf(m, m_part[(size_t)k*NM + j]);
  float z = 0.f;
#pragma unroll
  for (int k = 0; k < KSPLIT; ++k)
    z += z_part[(size_t)k*NM + j] * __expf(m_part[(size_t)k*NM + j] - m);
  m_c[j] = m;
  iz_c[j] = 1.0f / z;
}

__global__ __launch_bounds__(256, 2)
void pass2_fb(const u16* __restrict__ Qh, const u16* __restrict__ Ql,
              const u16* __restrict__ Pht, const u16* __restrict__ Plt,
              const float* __restrict__ temp,
              const int* __restrict__ cntb, const int* __restrict__ offb,
              const float* __restrict__ m_c, const float* __restrict__ iz_c,
              float* __restrict__ out) {
  int bid = blockIdx.x;
  int kt = (bid & 7) * 8 + ((bid >> 3) & 7);
  int b = bid >> 6;
  int cb = cntb[b], ob = offb[b];
  int tid = threadIdx.x;
  if (cb == 0) { if (tid < BN) out[(size_t)b*NK + kt*BN + tid] = 0.f; return; }

  int wid = tid >> 6, lane = tid & 63;
  int wm = wid >> 1, wn = wid & 1;
  int fr = lane & 15, fq = lane >> 4;
  int psl = fq ^ ((fr >> 1) & 3);

  __shared__ u16 Ah[2][BM*32], Al[2][BM*32], Bh[2][BN*32], Bl[2][BN*32];
  __shared__ float mrow[BM], izrow[BM];
  __shared__ float red[2][BN];

  float invT = 1.0f / temp[0];
  int c0 = wid*128 + lane, c1 = c0 + 64;
  int rl0 = c0 >> 2, rl1 = c1 >> 2;
  int sl0 = (c0 & 3) ^ ((rl0 >> 1) & 3);
  int sl1 = (c1 & 3) ^ ((rl1 >> 1) & 3);

  const u16 *qh0, *qh1, *ql0, *ql1;
  auto setq = [&](int t0) {
    int g0 = ob + min(t0 + rl0, cb - 1);
    int g1 = ob + min(t0 + rl1, cb - 1);
    qh0 = Qh + (size_t)g0*ND + sl0*8;
    qh1 = Qh + (size_t)g1*ND + sl1*8;
    ql0 = Ql + (size_t)g0*ND + sl0*8;
    ql1 = Ql + (size_t)g1*ND + sl1*8;
  };
  auto stage = [&](int bf, int dt) {
    int dq = dt * 32;
    size_t pofs = (size_t)kt*NDSTEP*4096 + (size_t)dt*4096;
    const u16* ph = Pht + pofs;
    const u16* pl = Plt + pofs;
    int w = wid*1024;
    gload16(qh0 + dq, &Ah[bf][w]);          gload16(qh1 + dq, &Ah[bf][w+512]);
    gload16(ql0 + dq, &Al[bf][w]);          gload16(ql1 + dq, &Al[bf][w+512]);
    gload16(ph + (size_t)c0*8, &Bh[bf][w]); gload16(ph + (size_t)c1*8, &Bh[bf][w+512]);
    gload16(pl + (size_t)c0*8, &Bl[bf][w]); gload16(pl + (size_t)c1*8, &Bl[bf][w+512]);
  };

  float rc[4] = {0.f, 0.f, 0.f, 0.f};

  setq(0);
  stage(0, 0);
  __syncthreads();
  int buf = 0;

  for (int t0 = 0; t0 < cb; t0 += BM) {
    if (tid < BM) {
      int j = min(t0 + tid, cb - 1);
      mrow[tid] = m_c[ob + j];
      izrow[tid] = (t0 + tid < cb) ? iz_c[ob + j] : 0.f;
    }

    f32x4 acc[4][4];
#pragma unroll
    for (int i = 0; i < 4; ++i)
#pragma unroll
      for (int j = 0; j < 4; ++j) acc[i][j] = f32x4{0.f, 0.f, 0.f, 0.f};

    for (int dt = 0; dt < NDSTEP; ++dt) {
      if (dt < NDSTEP-1) {
        stage(buf^1, dt+1);
      } else if (t0 + BM < cb) {
        setq(t0 + BM);
        stage(buf^1, 0);
      }
      mfma_step(Ah[buf], Al[buf], Bh[buf], Bl[buf], wm, wn, fr, psl, acc);
      __syncthreads();
      buf ^= 1;
    }

#pragma unroll
    for (int mi = 0; mi < 4; ++mi)
#pragma unroll
      for (int r = 0; r < 4; ++r) {
        int slot = wm*64 + mi*16 + fq*4 + r;
        float mv = mrow[slot], izv = izrow[slot];
#pragma unroll
        for (int ni = 0; ni < 4; ++ni)
          rc[ni] = fmaxf(rc[ni], __expf(acc[mi][ni][r]*invT - mv) * izv);
      }
    __syncthreads();
  }

#pragma unroll
  for (int ni = 0; ni < 4; ++ni) {
    rc[ni] = fmaxf(rc[ni], __shfl_xor(rc[ni], 16));
    rc[ni] = fmaxf(rc[ni], __shfl_xor(rc[ni], 32));
  }
  if (fq == 0) {
#pragma unroll
    for (int ni = 0; ni < 4; ++ni) red[wm][wn*64 + ni*16 + fr] = rc[ni];
  }
  __syncthreads();
  if (tid < BN) out[(size_t)b*NK + kt*BN + tid] = fmaxf(red[0][tid], red[1][tid]);
}

__global__ __launch_bounds__(256)
void normalize_rows(float* __restrict__ out) {
  int b = blockIdx.x;
  int tid = threadIdx.x;
  float* row = out + (size_t)b * NK;
  float ss = 0.f;
  for (int i = tid; i < NK; i += 256) { float v = row[i]; ss = fmaf(v, v, ss); }
#pragma unroll
  for (int o = 1; o < 64; o <<= 1) ss += __shfl_xor(ss, o);
  __shared__ float wsum[4];
  int lane = tid & 63, wv = tid >> 6;
  if (lane == 0) wsum[wv] = ss;
  __syncthreads();
  float tot = wsum[0] + wsum[1] + wsum[2] + wsum[3];
  float inv = 1.0f / fmaxf(sqrtf(tot), 1e-12f);
  for (int i = tid; i < NK; i += 256) row[i] *= inv;
}

// ---------------------------------------------------------------------------
extern "C" void kernel_launch(void* const* d_in, const int* in_sizes, int n_in,
                              void* d_out, int out_size, void* d_ws, size_t ws_size,
                              hipStream_t stream) {
  const float* q    = (const float*)d_in[0];
  const float* p    = (const float*)d_in[1];
  const float* temp = (const float*)d_in[2];
  const int*   mask = (const int*)d_in[3];
  float* out = (float*)d_out;
  char* W = (char*)d_ws;

  const size_t QHL = (size_t)NM*ND, PHL = (size_t)NK*ND;
  auto al = [](size_t x){ return (x + 255) & ~(size_t)255; };

  // streaming layout for chunk size CR
  size_t o_mp, o_zp, o_cl, o_sa, o_vg, o_ct, o_qh, o_ql, o_ph, o_pl, o_lg, need;
  auto layout = [&](size_t CR) {
    size_t off = 0;
    o_mp = off; off = al(off + 64*CR*4);
    o_zp = off; off = al(off + 64*CR*4);
    o_cl = off; off = al(off + CR*4);
    o_sa = off; off = al(off + (size_t)NB*NK*4);
    o_vg = off; off = al(off + (size_t)NM*4);
    o_ct = off; off = al(off + (2*NB + 2)*4);
    o_qh = off; off = al(off + QHL*2);
    o_ql = off; off = al(off + QHL*2);
    o_ph = off; off = al(off + PHL*2);
    o_pl = off; off = al(off + PHL*2);
    o_lg = off; off = al(off + CR*(size_t)NK*2);
    need = off;
  };

  int CH = 0;
  const int opts[5] = {16384, 8192, 4096, 2048, 1024};
  for (int i = 0; i < 5; ++i) {
    layout((size_t)opts[i]);
    if (ws_size >= need) { CH = opts[i]; break; }
  }

  if (CH > 0) {
    layout((size_t)CH);
    float* m_part = (float*)(W + o_mp);
    float* z_part = (float*)(W + o_zp);
    float* c_loc  = (float*)(W + o_cl);
    float* sacc   = (float*)(W + o_sa);
    int*   vg     = (int*)(W + o_vg);
    int*   cntp   = (int*)(W + o_ct);
    int*   offp   = cntp + NB;
    int*   total  = offp + NB;
    u16*   Qh     = (u16*)(W + o_qh);
    u16*   Ql     = (u16*)(W + o_ql);
    u16*   Pht    = (u16*)(W + o_ph);
    u16*   Plt    = (u16*)(W + o_pl);
    u16*   Lg     = (u16*)(W + o_lg);

    compact_pad<<<1, 512, 0, stream>>>(mask, vg, cntp, offp, total);
    convert_q<<<(NM*(ND/8))/256, 256, 0, stream>>>(q, vg, total, Qh, Ql);
    convert_p<<<(64*NDSTEP*512)/256, 256, 0, stream>>>(p, Pht, Plt);

    int nch = NM / CH;
    for (int c = 0; c < nch; ++c) {
      pass1s<<<(CH/128)*64, 256, 0, stream>>>(Qh, Ql, Pht, Plt, temp, total,
                                              c*CH, CH, m_part, z_part, Lg);
      combines<<<CH/256, 256, 0, stream>>>(m_part, z_part, total, c*CH, CH, c_loc);
      pass2s<<<64*NB, 256, 0, stream>>>(Lg, m_part, c_loc, cntp, offp,
                                        c*CH, CH, c, sacc);
    }
    normalize_s<<<NB, 256, 0, stream>>>(sacc, out);
  } else {
    // ---- fallback: exact R5 layout & kernels (needs ~78 MB) ----
    float* wsf    = (float*)d_ws;
    float* m_c    = wsf;
    float* iz_c   = wsf + NM;
    float* m_part = wsf + 2*NM;
    float* z_part = wsf + 2*NM + (size_t)KSPLIT*NM;
    int*   vg     = (int*)(wsf + 2*NM + (size_t)2*KSPLIT*NM);
    int*   cntb   = vg + NM;
    int*   offb   = cntb + NB;
    int*   total  = offb + NB;
    u16*   Qh     = (u16*)(wsf + (size_t)(2 + 2*KSPLIT + 1)*NM + 128);
    u16*   Ql     = Qh + QHL;
    u16*   Pht    = Ql + QHL;
    u16*   Plt    = Pht + PHL;

    compact_all<<<1, 512, 0, stream>>>(mask, vg, cntb, offb, total);
    convert_q<<<(NM*(ND/8))/256, 256, 0, stream>>>(q, vg, total, Qh, Ql);
    convert_p<<<(64*NDSTEP*512)/256, 256, 0, stream>>>(p, Pht, Plt);
    pass1_fb<<<(NM/BM)*KSPLIT, 256, 0, stream>>>(Qh, Ql, Pht, Plt, temp, total,
                                                 m_part, z_part);
    combine_fb<<<NM/256, 256, 0, stream>>>(m_part, z_part, total, m_c, iz_c);
    pass2_fb<<<64*NB, 256, 0, stream>>>(Qh, Ql, Pht, Plt, temp, cntb, offb,
                                        m_c, iz_c, out);
    normalize_rows<<<NB, 256, 0, stream>>>(out);
  }
}